// Round 8
// baseline (271.315 us; speedup 1.0000x reference)
//
#include <hip/hip_runtime.h>
#include <hip/hip_bf16.h>

#define NROWS 100000
#define FT 256
#define NC 16
#define NBLK 512          // k_accum blocks (cached path)
#define NSL 8             // stage-2 reduce slices
#define SLICE (NBLK / NSL)

// fixed-point scale for class-sum accumulation
#define FPSCALE 1048576.0f      // 2^20
#define FPINV   (1.0f / 1048576.0f)

// ---------------- cached-path ws layout (4-byte words) ----------------
#define CW_AVEB 0                       // 2048 words = 4096 bf16 ave [c][f]
#define CW_NRM  2048                    // 16 floats
#define CW_PCNT 2064                    // NBLK*NC ints
#define CW_ST2C (CW_PCNT + NBLK*NC)     // NSL*NC ints
#define CW_ST2  (CW_ST2C + NSL*NC)      // NSL*NC*FT ints
#define CW_PART (CW_ST2 + NSL*NC*FT)    // NBLK*NC*FT ints
#define CW_RAWB (CW_PART + NBLK*NC*FT)  // NROWS*FT bf16
#define CW_TOTAL (CW_RAWB + (NROWS*FT)/2)
#define CACHED_NEED_BYTES ((size_t)CW_TOTAL * 4)
// extended layout: per-row self-dot (fp32), +400 KB
#define CW_NRM2 CW_TOTAL
#define CW_TOTAL2 (CW_NRM2 + NROWS)
#define CACHED2_NEED_BYTES ((size_t)CW_TOTAL2 * 4)

// ---------------- fallback ws layout (R3, 4-byte words) ----------------
#define WS_COEF 0
#define WS_SUMS 256
#define WS_CNTS 4352
#define WS_AVEB 4368
#define WS_NRM  6416

typedef float f32x4 __attribute__((ext_vector_type(4)));
typedef short bf16x8 __attribute__((ext_vector_type(8)));

static __device__ __forceinline__ float bfbits2f(unsigned int u16) {
    union { unsigned int i; float f; } v; v.i = u16 << 16; return v.f;
}
static __device__ __forceinline__ unsigned short f2bf(float f) {
    union { float f; unsigned int i; } v; v.f = f;
    unsigned int u = v.i;
    u += 0x7fffu + ((u >> 16) & 1u);   // RNE
    return (unsigned short)(u >> 16);
}

// ======================= cached path =======================

// K1c v8 = v7 (NT input loads, register class-sums, no atomics) with:
//  - SWITCH-based class accumulation: label is a wave-uniform SGPR, so
//    switch(ls) is SCALAR branching; each case does 4 v_adds with static
//    indices. Replaces 64 masked v_fmacs/row (~60% VALU cut). Bit-exact.
//  - 512 threads/block (8 waves, one full row each) -> 16 waves/CU.
//  ws layout, NBLK, reduce chain unchanged.
template<int USE_NRM>
__global__ __launch_bounds__(512) void k_accum_ct(
    const float* __restrict__ seq,
    const float* __restrict__ seq1,
    const int* __restrict__ labels,
    const float* __restrict__ p1,
    const float* __restrict__ p2,
    const float* __restrict__ p3,
    const float* __restrict__ wwp,
    const float* __restrict__ wwf,
    const float* __restrict__ wdp,
    const float* __restrict__ a4p,
    float* __restrict__ ws)
{
    __shared__ __align__(16) float scoef[FT];
    __shared__ __align__(16) float lsumf[NC * FT];   // 16 KB block partial
    __shared__ int lcnti[8 * NC];
    const int tid = threadIdx.x;

    if (tid < FT) {
        float z = wwp[0] * p1[tid] + wwp[1] * p2[tid] + wwp[2] * p3[tid];
        float w = (z > 0.f) ? (1.f + z) : __expf(z);   // 1 + elu(z)
        scoef[tid] = wwf[0] * w + wwf[1] * wdp[tid];
    }
    __syncthreads();

    const int wv = tid >> 6;      // wave 0..7
    const int l  = tid & 63;      // lane
    const int fl = l * 4;         // feature base (4 feats/lane)

    float cof[4];
    {
        const float4 c4 = *(const float4*)(scoef + fl);
        cof[0] = c4.x; cof[1] = c4.y; cof[2] = c4.z; cof[3] = c4.w;
    }
    const float a4v = a4p[0];
    unsigned int* rawb = (unsigned int*)(ws + CW_RAWB);
    float* nrm2 = ws + CW_NRM2;

    float acc[NC][4];
#pragma unroll
    for (int c = 0; c < NC; ++c)
#pragma unroll
        for (int i = 0; i < 4; ++i) acc[c][i] = 0.f;
    int scnt[NC];
#pragma unroll
    for (int c = 0; c < NC; ++c) scnt[c] = 0;

    const int wg = blockIdx.x * 8 + wv;          // global wave id 0..4095
    const int NQ = NROWS / 4;                    // 25000 row-quads
    for (int q = wg; q < NQ; q += NBLK * 8) {
        const int r0 = q * 4;
        // issue all 12 loads up front; seq/seq1 non-temporal (read-once)
        int lb[4]; f32x4 s4[4], t4[4];
#pragma unroll
        for (int j = 0; j < 4; ++j) {
            lb[j] = labels[r0 + j];
            s4[j] = __builtin_nontemporal_load(
                        (const f32x4*)(seq  + (r0 + j) * FT + fl));
            t4[j] = __builtin_nontemporal_load(
                        (const f32x4*)(seq1 + (r0 + j) * FT + fl));
        }
#pragma unroll
        for (int j = 0; j < 4; ++j) {
            float v[4];
#pragma unroll
            for (int i = 0; i < 4; ++i) {
                float u = cof[i] * s4[j][i];
                float r = (u > 0.f) ? u : (__expf(u) - 1.f);   // elu
                v[i] = r + a4v * t4[j][i];
            }
            unsigned short b[4];
#pragma unroll
            for (int i = 0; i < 4; ++i) b[i] = f2bf(v[i]);
            // bf16 cache store (8B/lane, 512B/wave contiguous) — NORMAL
            // store so k_out hits it in L2/L3
            uint2 pk;
            pk.x = (unsigned int)b[0] | ((unsigned int)b[1] << 16);
            pk.y = (unsigned int)b[2] | ((unsigned int)b[3] << 16);
            *(uint2*)(rawb + ((r0 + j) * FT + fl) / 2) = pk;

            if (USE_NRM) {
                // row self-dot over the SAME bf16-rounded values the
                // out-phase MFMA would square
                float rq = 0.f;
#pragma unroll
                for (int i = 0; i < 4; ++i) {
                    float vb = bfbits2f(b[i]);
                    rq = fmaf(vb, vb, rq);
                }
#pragma unroll
                for (int o = 1; o < 64; o <<= 1)
                    rq += __shfl_xor(rq, o, 64);
                if (l == 0) nrm2[r0 + j] = rq;
            }

            // class-sum: label wave-uniform (SGPR) -> SCALAR 16-way switch;
            // each case = 4 v_adds, statically indexed (register-resident).
            // Bit-exact vs masked fmaf (adding v[i] == fmaf(1,v[i],acc);
            // skipped classes previously added exact +0).
            const int ls = __builtin_amdgcn_readfirstlane(lb[j]);
#define ACC_CASE(C) case C: \
            acc[C][0] += v[0]; acc[C][1] += v[1]; \
            acc[C][2] += v[2]; acc[C][3] += v[3]; break;
            switch (ls) {
                ACC_CASE(0)  ACC_CASE(1)  ACC_CASE(2)  ACC_CASE(3)
                ACC_CASE(4)  ACC_CASE(5)  ACC_CASE(6)  ACC_CASE(7)
                ACC_CASE(8)  ACC_CASE(9)  ACC_CASE(10) ACC_CASE(11)
                ACC_CASE(12) ACC_CASE(13) ACC_CASE(14) ACC_CASE(15)
            }
#undef ACC_CASE
#pragma unroll
            for (int c = 0; c < NC; ++c)
                scnt[c] += (ls == c) ? 1 : 0;              // SALU
        }
    }

    // per-wave counts -> LDS
    if (l == 0) {
#pragma unroll
        for (int c = 0; c < NC; ++c) lcnti[wv * NC + c] = scnt[c];
    }

    // serial wave-by-wave reduce into lsumf (plain ds ops, deterministic)
    for (int w = 0; w < 8; ++w) {
        if (wv == w) {
#pragma unroll
            for (int c = 0; c < NC; ++c) {
                float4* p = (float4*)(lsumf + c * FT + fl);
                if (w == 0) {
                    float4 nv; nv.x = acc[c][0]; nv.y = acc[c][1];
                    nv.z = acc[c][2]; nv.w = acc[c][3];
                    *p = nv;
                } else {
                    float4 old = *p;
                    old.x += acc[c][0]; old.y += acc[c][1];
                    old.z += acc[c][2]; old.w += acc[c][3];
                    *p = old;
                }
            }
        }
        __syncthreads();
    }

    // fixed-point int partials, [block][c][f] — NT (read-once)
    int* gpart = (int*)(ws + CW_PART) + blockIdx.x * (NC * FT);
    for (int idx = tid; idx < NC * FT; idx += 512)
        __builtin_nontemporal_store(__float2int_rn(lsumf[idx] * FPSCALE),
                                    gpart + idx);
    if (tid < NC) {
        int cc = 0;
#pragma unroll
        for (int w = 0; w < 8; ++w) cc += lcnti[w * NC + tid];
        __builtin_nontemporal_store(cc,
            (int*)(ws + CW_PCNT) + blockIdx.x * NC + tid);
    }
}

// K1.5c stage 1: 128 blocks = (class, slice); sum 64 partials + counts
__global__ __launch_bounds__(256) void k_reduce1(float* __restrict__ ws)
{
    const int c = blockIdx.x >> 3;   // class
    const int r = blockIdx.x & 7;    // slice
    const int f = threadIdx.x;
    const int p0 = r * SLICE;
    const int* gpart = (const int*)(ws + CW_PART);
    int acc = 0;
#pragma unroll
    for (int p = 0; p < SLICE; ++p)
        acc += __builtin_nontemporal_load(
            gpart + (p0 + p) * (NC * FT) + c * FT + f);
    ((int*)(ws + CW_ST2))[(r * NC + c) * FT + f] = acc;

    if (f < SLICE) {
        int cc = ((const int*)(ws + CW_PCNT))[(p0 + f) * NC + c];
#pragma unroll
        for (int o = 32; o > 0; o >>= 1) cc += __shfl_down(cc, o, 64);
        if (f == 0) ((int*)(ws + CW_ST2C))[r * NC + c] = cc;
    }
}

// K1.5c stage 2: 16 blocks (one per class): 8-way sum -> ave bf16 + norm
__global__ __launch_bounds__(256) void k_reduce2(float* __restrict__ ws)
{
    __shared__ float red[256];
    const int c = blockIdx.x;
    const int f = threadIdx.x;
    const int* st2  = (const int*)(ws + CW_ST2);
    const int* st2c = (const int*)(ws + CW_ST2C);
    long long isum = 0;
    int cnt = 0;
#pragma unroll
    for (int s = 0; s < NSL; ++s) {
        isum += (long long)st2[(s * NC + c) * FT + f];
        cnt  += st2c[s * NC + c];
    }
    float a = ((float)isum * FPINV) / fmaxf((float)cnt, 1.f);
    unsigned short ab = f2bf(a);
    ((unsigned short*)(ws + CW_AVEB))[c * FT + f] = ab;
    float af = bfbits2f(ab);

    red[f] = af * af;
    __syncthreads();
#pragma unroll
    for (int s = 128; s > 0; s >>= 1) {
        if (f < s) red[f] += red[f + s];
        __syncthreads();
    }
    if (f == 0) ws[CW_NRM + c] = sqrtf(red[0]);
}

// K2c: cached bf16 rawret + (USE_NRM) precomputed row self-dots ->
// single MFMA chain (accC only). Cosine + softmax via width-16 shuffles.
template<int USE_NRM>
__global__ __launch_bounds__(256) void k_out_ct(
    const float* __restrict__ ws,
    float* __restrict__ out)
{
    const int tid = threadIdx.x;
    const int lane = tid & 63;
    const int wv   = tid >> 6;
    const int c = lane & 15;   // class (B col) == A row index m
    const int g = lane >> 4;   // k-quad

    const unsigned short* aveb = (const unsigned short*)(ws + CW_AVEB);
    const unsigned short* rawb = (const unsigned short*)(ws + CW_RAWB);
    const float* nrm2 = ws + CW_NRM2;
    bf16x8 bfrag[8];
#pragma unroll
    for (int kc = 0; kc < 8; ++kc)
        bfrag[kc] = *(const bf16x8*)(aveb + c * FT + kc * 32 + g * 8);
    const float na = ws[CW_NRM + c];

    const int ntiles = NROWS / 16;   // 6250 exact
    for (int tile = blockIdx.x * 4 + wv; tile < ntiles; tile += gridDim.x * 4) {
        const int rowbase = tile * 16;
        const int arow = rowbase + c;     // A row m = lane&15
        float sdq[4];
        if (USE_NRM) {
#pragma unroll
            for (int q = 0; q < 4; ++q)
                sdq[q] = nrm2[rowbase + g * 4 + q];   // broadcast load
        }
        f32x4 accC = {0.f, 0.f, 0.f, 0.f};
        f32x4 accS = {0.f, 0.f, 0.f, 0.f};
#pragma unroll
        for (int kc = 0; kc < 8; ++kc) {
            bf16x8 afrag = *(const bf16x8*)(rawb + arow * FT + kc * 32 + g * 8);
            accC = __builtin_amdgcn_mfma_f32_16x16x32_bf16(afrag, bfrag[kc], accC, 0, 0, 0);
            if (!USE_NRM)
                accS = __builtin_amdgcn_mfma_f32_16x16x32_bf16(afrag, afrag, accS, 0, 0, 0);
        }
        // C/D layout: col=lane&15, row=g*4+reg; self-dot of row 4g+q at lane 20g+q.
#pragma unroll
        for (int q = 0; q < 4; ++q) {
            const float sd = USE_NRM ? sdq[q] : __shfl(accS[q], g * 20 + q, 64);
            const float nr = sqrtf(fmaxf(sd, 0.f));
            const float denom = fmaxf(nr * na, 1e-8f);
            float cosv = accC[q] / denom;
            float mx = cosv;
#pragma unroll
            for (int o = 1; o < 16; o <<= 1) mx = fmaxf(mx, __shfl_xor(mx, o, 16));
            const float e = __expf(cosv - mx);
            float s = e;
#pragma unroll
            for (int o = 1; o < 16; o <<= 1) s += __shfl_xor(s, o, 16);
            out[(rowbase + g * 4 + q) * NC + c] = e / s;
        }
    }
}

// ======================= fallback path (R3, verbatim behavior) =======================

__global__ void k_prep(const float* __restrict__ p1,
                       const float* __restrict__ p2,
                       const float* __restrict__ p3,
                       const float* __restrict__ wwp,
                       const float* __restrict__ wwf,
                       const float* __restrict__ wdp,
                       float* __restrict__ ws)
{
    int f = threadIdx.x;
    float z = wwp[0] * p1[f] + wwp[1] * p2[f] + wwp[2] * p3[f];
    float weight = (z > 0.f) ? (1.f + z) : __expf(z);
    ws[WS_COEF + f] = wwf[0] * weight + wwf[1] * wdp[f];
}

__global__ __launch_bounds__(1024) void k_accum(
    const float* __restrict__ seq,
    const float* __restrict__ seq1,
    const int* __restrict__ labels,
    const float* __restrict__ a4p,
    float* __restrict__ ws)
{
    __shared__ int lsum[NC * FT];
    __shared__ int lcnt[NC];
    const int tid = threadIdx.x;
    for (int i = tid; i < NC * FT; i += 1024) lsum[i] = 0;
    if (tid < NC) lcnt[tid] = 0;
    __syncthreads();

    const int rr = tid >> 5;
    const int m  = tid & 31;
    const int f0 = m * 8;
    const int mh = m >> 2;
    int off[8];
#pragma unroll
    for (int i = 0; i < 8; ++i) off[i] = (i + mh) & 7;

    float cof[8];
    {
        const float4 c0 = *(const float4*)(ws + WS_COEF + f0);
        const float4 c1 = *(const float4*)(ws + WS_COEF + f0 + 4);
        cof[0]=c0.x; cof[1]=c0.y; cof[2]=c0.z; cof[3]=c0.w;
        cof[4]=c1.x; cof[5]=c1.y; cof[6]=c1.z; cof[7]=c1.w;
    }
    const float a4v = a4p[0];

    for (int row = blockIdx.x * 32 + rr; row < NROWS; row += gridDim.x * 32) {
        const int lab = labels[row];
        const float4 sa  = *(const float4*)(seq  + row * FT + f0);
        const float4 sb  = *(const float4*)(seq  + row * FT + f0 + 4);
        const float4 ta  = *(const float4*)(seq1 + row * FT + f0);
        const float4 tb  = *(const float4*)(seq1 + row * FT + f0 + 4);
        const float s[8]  = {sa.x,sa.y,sa.z,sa.w, sb.x,sb.y,sb.z,sb.w};
        const float t[8]  = {ta.x,ta.y,ta.z,ta.w, tb.x,tb.y,tb.z,tb.w};
        int* base = lsum + lab * FT + f0;
#pragma unroll
        for (int i = 0; i < 8; ++i) {
            float u = cof[i] * s[i];
            float r = (u > 0.f) ? u : (__expf(u) - 1.f);
            atomicAdd(base + off[i], __float2int_rn((r + a4v * t[i]) * FPSCALE));
        }
        if (m == 0) atomicAdd(&lcnt[lab], 1);
    }
    __syncthreads();

    int* gsum = (int*)(ws + WS_SUMS);
    for (int idx = tid; idx < NC * FT; idx += 1024) {
        int p  = idx & 255;
        int mm = p >> 3;
        int r  = p & 7;
        int f  = (p & ~7) | ((r - (mm >> 2)) & 7);
        atomicAdd(gsum + (idx & ~255) + f, lsum[idx]);
    }
    if (tid < NC) atomicAdd((int*)(ws + WS_CNTS) + tid, lcnt[tid]);
}

__global__ void k_final(float* __restrict__ ws)
{
    __shared__ float nacc[NC];
    const int f = threadIdx.x;
    if (f < NC) nacc[f] = 0.f;
    __syncthreads();
    const int* gsum = (const int*)(ws + WS_SUMS);
    const int* gcnt = (const int*)(ws + WS_CNTS);
    unsigned short* aveb = (unsigned short*)(ws + WS_AVEB);
#pragma unroll
    for (int c = 0; c < NC; ++c) {
        float cnt = (float)gcnt[c];
        float a = ((float)gsum[c * FT + f] * FPINV) / fmaxf(cnt, 1.f);
        unsigned short ab = f2bf(a);
        aveb[c * FT + f] = ab;
        float af = bfbits2f(ab);
        atomicAdd(&nacc[c], af * af);
    }
    __syncthreads();
    if (f < NC) ws[WS_NRM + f] = sqrtf(nacc[f]);
}

__global__ __launch_bounds__(256) void k_out(
    const float* __restrict__ seq,
    const float* __restrict__ seq1,
    const float* __restrict__ a4p,
    const float* __restrict__ ws,
    float* __restrict__ out)
{
    __shared__ __align__(16) float scoef[FT];
    const int tid = threadIdx.x;
    for (int i = tid; i < FT; i += 256) scoef[i] = ws[WS_COEF + i];
    __syncthreads();

    const int lane = tid & 63;
    const int wv   = tid >> 6;
    const int c = lane & 15;
    const int g = lane >> 4;

    const unsigned short* aveb = (const unsigned short*)(ws + WS_AVEB);
    bf16x8 bfrag[8];
#pragma unroll
    for (int kc = 0; kc < 8; ++kc)
        bfrag[kc] = *(const bf16x8*)(aveb + c * FT + kc * 32 + g * 8);
    const float na  = ws[WS_NRM + c];
    const float a4v = a4p[0];

    const int ntiles = NROWS / 16;
    for (int tile = blockIdx.x * 4 + wv; tile < ntiles; tile += gridDim.x * 4) {
        const int rowbase = tile * 16;
        const int arow = rowbase + c;
        f32x4 accC = {0.f, 0.f, 0.f, 0.f};
        f32x4 accS = {0.f, 0.f, 0.f, 0.f};
#pragma unroll
        for (int kc = 0; kc < 8; ++kc) {
            const int k0 = kc * 32 + g * 8;
            const float4 sa = *(const float4*)(seq  + arow * FT + k0);
            const float4 sb = *(const float4*)(seq  + arow * FT + k0 + 4);
            const float4 ta = *(const float4*)(seq1 + arow * FT + k0);
            const float4 tb = *(const float4*)(seq1 + arow * FT + k0 + 4);
            const float4 c0 = *(const float4*)(scoef + k0);
            const float4 c1 = *(const float4*)(scoef + k0 + 4);
            const float s[8]  = {sa.x,sa.y,sa.z,sa.w, sb.x,sb.y,sb.z,sb.w};
            const float t[8]  = {ta.x,ta.y,ta.z,ta.w, tb.x,tb.y,tb.z,tb.w};
            const float cf[8] = {c0.x,c0.y,c0.z,c0.w, c1.x,c1.y,c1.z,c1.w};
            bf16x8 afrag;
#pragma unroll
            for (int i = 0; i < 8; ++i) {
                float u = cf[i] * s[i];
                float r = (u > 0.f) ? u : (__expf(u) - 1.f);
                afrag[i] = (short)f2bf(r + a4v * t[i]);
            }
            accC = __builtin_amdgcn_mfma_f32_16x16x32_bf16(afrag, bfrag[kc], accC, 0, 0, 0);
            accS = __builtin_amdgcn_mfma_f32_16x16x32_bf16(afrag, afrag,     accS, 0, 0, 0);
        }
#pragma unroll
        for (int q = 0; q < 4; ++q) {
            const float sd = __shfl(accS[q], g * 20 + q, 64);
            const float nr = sqrtf(fmaxf(sd, 0.f));
            const float denom = fmaxf(nr * na, 1e-8f);
            float cosv = accC[q] / denom;
            float mx = cosv;
#pragma unroll
            for (int o = 1; o < 16; o <<= 1) mx = fmaxf(mx, __shfl_xor(mx, o, 16));
            const float e = __expf(cosv - mx);
            float s = e;
#pragma unroll
            for (int o = 1; o < 16; o <<= 1) s += __shfl_xor(s, o, 16);
            out[(rowbase + g * 4 + q) * NC + c] = e / s;
        }
    }
}

extern "C" void kernel_launch(void* const* d_in, const int* in_sizes, int n_in,
                              void* d_out, int out_size, void* d_ws, size_t ws_size,
                              hipStream_t stream)
{
    const float* seq  = (const float*)d_in[0];
    const float* seq1 = (const float*)d_in[1];
    const int*   lab  = (const int*)d_in[2];
    const float* p1   = (const float*)d_in[3];
    const float* p2   = (const float*)d_in[4];
    const float* p3   = (const float*)d_in[5];
    const float* wwp  = (const float*)d_in[6];
    const float* wwf  = (const float*)d_in[7];
    const float* wdp  = (const float*)d_in[8];
    const float* a4   = (const float*)d_in[9];
    float* ws  = (float*)d_ws;
    float* out = (float*)d_out;

    if (ws_size >= CACHED2_NEED_BYTES) {
        // full path: NT input loads + switch class-sum + row-norm precompute
        k_accum_ct<1><<<NBLK,     512, 0, stream>>>(seq, seq1, lab, p1, p2, p3,
                                                    wwp, wwf, wdp, a4, ws);
        k_reduce1   <<<NC * NSL,  256, 0, stream>>>(ws);
        k_reduce2   <<<NC,        256, 0, stream>>>(ws);
        k_out_ct<1> <<<1568,      256, 0, stream>>>(ws, out);
    } else if (ws_size >= CACHED_NEED_BYTES) {
        // middle: same chain without the nrm2 region
        k_accum_ct<0><<<NBLK,     512, 0, stream>>>(seq, seq1, lab, p1, p2, p3,
                                                    wwp, wwf, wdp, a4, ws);
        k_reduce1   <<<NC * NSL,  256, 0, stream>>>(ws);
        k_reduce2   <<<NC,        256, 0, stream>>>(ws);
        k_out_ct<0> <<<1568,      256, 0, stream>>>(ws, out);
    } else {
        // fallback: R3 structure
        hipMemsetAsync((char*)d_ws + WS_SUMS * sizeof(int), 0,
                       (NC * FT + NC) * sizeof(int), stream);
        k_prep <<<1,    256, 0, stream>>>(p1, p2, p3, wwp, wwf, wdp, ws);
        k_accum<<<512, 1024, 0, stream>>>(seq, seq1, lab, a4, ws);
        k_final<<<1,    256, 0, stream>>>(ws);
        k_out  <<<1568, 256, 0, stream>>>(seq, seq1, a4, ws, out);
    }
}

// Round 9
// 259.215 us; speedup vs baseline: 1.0467x; 1.0467x over previous
//
#include <hip/hip_runtime.h>
#include <hip/hip_bf16.h>

#define NROWS 100000
#define FT 256
#define NC 16
#define NBLK 512          // k_accum blocks (cached path)
#define NSL 8             // stage-2 reduce slices
#define SLICE (NBLK / NSL)

// fixed-point scale for class-sum accumulation
#define FPSCALE 1048576.0f      // 2^20
#define FPINV   (1.0f / 1048576.0f)

// ---------------- cached-path ws layout (4-byte words) ----------------
#define CW_AVEB 0                       // 2048 words = 4096 bf16 ave [c][f]
#define CW_NRM  2048                    // 16 floats
#define CW_PCNT 2064                    // NBLK*NC ints
#define CW_ST2C (CW_PCNT + NBLK*NC)     // NSL*NC ints
#define CW_ST2  (CW_ST2C + NSL*NC)      // NSL*NC*FT ints
#define CW_PART (CW_ST2 + NSL*NC*FT)    // NBLK*NC*FT ints
#define CW_RAWB (CW_PART + NBLK*NC*FT)  // NROWS*FT bf16
#define CW_TOTAL (CW_RAWB + (NROWS*FT)/2)
#define CACHED_NEED_BYTES ((size_t)CW_TOTAL * 4)
// extended layout: per-row self-dot (fp32), +400 KB
#define CW_NRM2 CW_TOTAL
#define CW_TOTAL2 (CW_NRM2 + NROWS)
#define CACHED2_NEED_BYTES ((size_t)CW_TOTAL2 * 4)

// ---------------- fallback ws layout (R3, 4-byte words) ----------------
#define WS_COEF 0
#define WS_SUMS 256
#define WS_CNTS 4352
#define WS_AVEB 4368
#define WS_NRM  6416

typedef float f32x4 __attribute__((ext_vector_type(4)));
typedef short bf16x8 __attribute__((ext_vector_type(8)));

static __device__ __forceinline__ float bfbits2f(unsigned int u16) {
    union { unsigned int i; float f; } v; v.i = u16 << 16; return v.f;
}
static __device__ __forceinline__ unsigned short f2bf(float f) {
    union { float f; unsigned int i; } v; v.f = f;
    unsigned int u = v.i;
    u += 0x7fffu + ((u >> 16) & 1u);   // RNE
    return (unsigned short)(u >> 16);
}

// ======================= cached path =======================

// K1c v7 (REVERT to best-measured: 62.5 us accum, 259.6 us total):
// R2 structure (one wave = one full row, register class-sums via masked
// fmaf, no atomics) with:
//  - NON-TEMPORAL LOADS of seq/seq1 (read-once per iteration; bypassing
//    cache allocation broke the 2.3 TB/s mixed-tier wall: 87 -> 62.5 us)
//  - rawb cached with NORMAL stores (k_out consumes from L2/L3)
//  - NT partial stores (read-once by reduce1)
//  - USE_NRM: per-row self-dot reduced in-register (same bf16-rounded
//    values the out-phase MFMA would square) -> halves k_out MFMA work.
// NOTE (R8 lesson): switch-based class-sum regressed (VGPR 76->128);
// masked fmaf keeps regalloc tight and fmacs are only ~8% of issue slots.
template<int USE_NRM>
__global__ __launch_bounds__(256) void k_accum_ct(
    const float* __restrict__ seq,
    const float* __restrict__ seq1,
    const int* __restrict__ labels,
    const float* __restrict__ p1,
    const float* __restrict__ p2,
    const float* __restrict__ p3,
    const float* __restrict__ wwp,
    const float* __restrict__ wwf,
    const float* __restrict__ wdp,
    const float* __restrict__ a4p,
    float* __restrict__ ws)
{
    __shared__ __align__(16) float scoef[FT];
    __shared__ __align__(16) float lsumf[NC * FT];   // 16 KB block partial
    __shared__ int lcnti[4 * NC];
    const int tid = threadIdx.x;

    // coef: tid covers FT exactly (256 threads)
    {
        float z = wwp[0] * p1[tid] + wwp[1] * p2[tid] + wwp[2] * p3[tid];
        float w = (z > 0.f) ? (1.f + z) : __expf(z);   // 1 + elu(z)
        scoef[tid] = wwf[0] * w + wwf[1] * wdp[tid];
    }
    __syncthreads();

    const int wv = tid >> 6;      // wave 0..3
    const int l  = tid & 63;      // lane
    const int fl = l * 4;         // feature base (4 feats/lane)

    float cof[4];
    {
        const float4 c4 = *(const float4*)(scoef + fl);
        cof[0] = c4.x; cof[1] = c4.y; cof[2] = c4.z; cof[3] = c4.w;
    }
    const float a4v = a4p[0];
    unsigned int* rawb = (unsigned int*)(ws + CW_RAWB);
    float* nrm2 = ws + CW_NRM2;

    float acc[NC][4];
#pragma unroll
    for (int c = 0; c < NC; ++c)
#pragma unroll
        for (int i = 0; i < 4; ++i) acc[c][i] = 0.f;
    int scnt[NC];
#pragma unroll
    for (int c = 0; c < NC; ++c) scnt[c] = 0;

    const int wg = blockIdx.x * 4 + wv;          // global wave id 0..2047
    const int NQ = NROWS / 4;                    // 25000 row-quads
    for (int q = wg; q < NQ; q += NBLK * 4) {
        const int r0 = q * 4;
        // issue all 12 loads up front; seq/seq1 non-temporal (read-once)
        int lb[4]; f32x4 s4[4], t4[4];
#pragma unroll
        for (int j = 0; j < 4; ++j) {
            lb[j] = labels[r0 + j];
            s4[j] = __builtin_nontemporal_load(
                        (const f32x4*)(seq  + (r0 + j) * FT + fl));
            t4[j] = __builtin_nontemporal_load(
                        (const f32x4*)(seq1 + (r0 + j) * FT + fl));
        }
#pragma unroll
        for (int j = 0; j < 4; ++j) {
            float v[4];
#pragma unroll
            for (int i = 0; i < 4; ++i) {
                float u = cof[i] * s4[j][i];
                float r = (u > 0.f) ? u : (__expf(u) - 1.f);   // elu
                v[i] = r + a4v * t4[j][i];
            }
            unsigned short b[4];
#pragma unroll
            for (int i = 0; i < 4; ++i) b[i] = f2bf(v[i]);
            // bf16 cache store (8B/lane, 512B/wave contiguous) — NORMAL
            // store so k_out hits it in L2/L3
            uint2 pk;
            pk.x = (unsigned int)b[0] | ((unsigned int)b[1] << 16);
            pk.y = (unsigned int)b[2] | ((unsigned int)b[3] << 16);
            *(uint2*)(rawb + ((r0 + j) * FT + fl) / 2) = pk;

            if (USE_NRM) {
                // row self-dot over the SAME bf16-rounded values the
                // out-phase MFMA would square
                float rq = 0.f;
#pragma unroll
                for (int i = 0; i < 4; ++i) {
                    float vb = bfbits2f(b[i]);
                    rq = fmaf(vb, vb, rq);
                }
#pragma unroll
                for (int o = 1; o < 64; o <<= 1)
                    rq += __shfl_xor(rq, o, 64);
                if (l == 0) nrm2[r0 + j] = rq;
            }

            // register class-sum: label is wave-uniform -> scalar mask
            const int ls = __builtin_amdgcn_readfirstlane(lb[j]);
#pragma unroll
            for (int c = 0; c < NC; ++c) {
                const float m = (ls == c) ? 1.0f : 0.0f;   // SALU cselect
#pragma unroll
                for (int i = 0; i < 4; ++i)
                    acc[c][i] = fmaf(m, v[i], acc[c][i]);
                scnt[c] += (ls == c) ? 1 : 0;              // SALU
            }
        }
    }

    // per-wave counts -> LDS
    if (l == 0) {
#pragma unroll
        for (int c = 0; c < NC; ++c) lcnti[wv * NC + c] = scnt[c];
    }

    // serial wave-by-wave reduce into lsumf (plain ds ops, deterministic)
    for (int w = 0; w < 4; ++w) {
        if (wv == w) {
#pragma unroll
            for (int c = 0; c < NC; ++c) {
                float4* p = (float4*)(lsumf + c * FT + fl);
                if (w == 0) {
                    float4 nv; nv.x = acc[c][0]; nv.y = acc[c][1];
                    nv.z = acc[c][2]; nv.w = acc[c][3];
                    *p = nv;
                } else {
                    float4 old = *p;
                    old.x += acc[c][0]; old.y += acc[c][1];
                    old.z += acc[c][2]; old.w += acc[c][3];
                    *p = old;
                }
            }
        }
        __syncthreads();
    }

    // fixed-point int partials, [block][c][f] — NT (read-once)
    int* gpart = (int*)(ws + CW_PART) + blockIdx.x * (NC * FT);
    for (int idx = tid; idx < NC * FT; idx += 256)
        __builtin_nontemporal_store(__float2int_rn(lsumf[idx] * FPSCALE),
                                    gpart + idx);
    if (tid < NC) {
        int cc = lcnti[tid] + lcnti[NC + tid] + lcnti[2 * NC + tid]
               + lcnti[3 * NC + tid];
        __builtin_nontemporal_store(cc,
            (int*)(ws + CW_PCNT) + blockIdx.x * NC + tid);
    }
}

// K1.5c stage 1: 128 blocks = (class, slice); sum 64 partials + counts
__global__ __launch_bounds__(256) void k_reduce1(float* __restrict__ ws)
{
    const int c = blockIdx.x >> 3;   // class
    const int r = blockIdx.x & 7;    // slice
    const int f = threadIdx.x;
    const int p0 = r * SLICE;
    const int* gpart = (const int*)(ws + CW_PART);
    int acc = 0;
#pragma unroll
    for (int p = 0; p < SLICE; ++p)
        acc += __builtin_nontemporal_load(
            gpart + (p0 + p) * (NC * FT) + c * FT + f);
    ((int*)(ws + CW_ST2))[(r * NC + c) * FT + f] = acc;

    if (f < SLICE) {
        int cc = ((const int*)(ws + CW_PCNT))[(p0 + f) * NC + c];
#pragma unroll
        for (int o = 32; o > 0; o >>= 1) cc += __shfl_down(cc, o, 64);
        if (f == 0) ((int*)(ws + CW_ST2C))[r * NC + c] = cc;
    }
}

// K1.5c stage 2: 16 blocks (one per class): 8-way sum -> ave bf16 + norm
__global__ __launch_bounds__(256) void k_reduce2(float* __restrict__ ws)
{
    __shared__ float red[256];
    const int c = blockIdx.x;
    const int f = threadIdx.x;
    const int* st2  = (const int*)(ws + CW_ST2);
    const int* st2c = (const int*)(ws + CW_ST2C);
    long long isum = 0;
    int cnt = 0;
#pragma unroll
    for (int s = 0; s < NSL; ++s) {
        isum += (long long)st2[(s * NC + c) * FT + f];
        cnt  += st2c[s * NC + c];
    }
    float a = ((float)isum * FPINV) / fmaxf((float)cnt, 1.f);
    unsigned short ab = f2bf(a);
    ((unsigned short*)(ws + CW_AVEB))[c * FT + f] = ab;
    float af = bfbits2f(ab);

    red[f] = af * af;
    __syncthreads();
#pragma unroll
    for (int s = 128; s > 0; s >>= 1) {
        if (f < s) red[f] += red[f + s];
        __syncthreads();
    }
    if (f == 0) ws[CW_NRM + c] = sqrtf(red[0]);
}

// K2c v7: cached bf16 rawret + (USE_NRM) precomputed row self-dots ->
// single MFMA chain (accC only). Cosine + softmax via width-16 shuffles.
template<int USE_NRM>
__global__ __launch_bounds__(256) void k_out_ct(
    const float* __restrict__ ws,
    float* __restrict__ out)
{
    const int tid = threadIdx.x;
    const int lane = tid & 63;
    const int wv   = tid >> 6;
    const int c = lane & 15;   // class (B col) == A row index m
    const int g = lane >> 4;   // k-quad

    const unsigned short* aveb = (const unsigned short*)(ws + CW_AVEB);
    const unsigned short* rawb = (const unsigned short*)(ws + CW_RAWB);
    const float* nrm2 = ws + CW_NRM2;
    bf16x8 bfrag[8];
#pragma unroll
    for (int kc = 0; kc < 8; ++kc)
        bfrag[kc] = *(const bf16x8*)(aveb + c * FT + kc * 32 + g * 8);
    const float na = ws[CW_NRM + c];

    const int ntiles = NROWS / 16;   // 6250 exact
    for (int tile = blockIdx.x * 4 + wv; tile < ntiles; tile += gridDim.x * 4) {
        const int rowbase = tile * 16;
        const int arow = rowbase + c;     // A row m = lane&15
        float sdq[4];
        if (USE_NRM) {
#pragma unroll
            for (int q = 0; q < 4; ++q)
                sdq[q] = nrm2[rowbase + g * 4 + q];   // broadcast load
        }
        f32x4 accC = {0.f, 0.f, 0.f, 0.f};
        f32x4 accS = {0.f, 0.f, 0.f, 0.f};
#pragma unroll
        for (int kc = 0; kc < 8; ++kc) {
            bf16x8 afrag = *(const bf16x8*)(rawb + arow * FT + kc * 32 + g * 8);
            accC = __builtin_amdgcn_mfma_f32_16x16x32_bf16(afrag, bfrag[kc], accC, 0, 0, 0);
            if (!USE_NRM)
                accS = __builtin_amdgcn_mfma_f32_16x16x32_bf16(afrag, afrag, accS, 0, 0, 0);
        }
        // C/D layout: col=lane&15, row=g*4+reg; self-dot of row 4g+q at lane 20g+q.
#pragma unroll
        for (int q = 0; q < 4; ++q) {
            const float sd = USE_NRM ? sdq[q] : __shfl(accS[q], g * 20 + q, 64);
            const float nr = sqrtf(fmaxf(sd, 0.f));
            const float denom = fmaxf(nr * na, 1e-8f);
            float cosv = accC[q] / denom;
            float mx = cosv;
#pragma unroll
            for (int o = 1; o < 16; o <<= 1) mx = fmaxf(mx, __shfl_xor(mx, o, 16));
            const float e = __expf(cosv - mx);
            float s = e;
#pragma unroll
            for (int o = 1; o < 16; o <<= 1) s += __shfl_xor(s, o, 16);
            out[(rowbase + g * 4 + q) * NC + c] = e / s;
        }
    }
}

// ======================= fallback path (R3, verbatim behavior) =======================

__global__ void k_prep(const float* __restrict__ p1,
                       const float* __restrict__ p2,
                       const float* __restrict__ p3,
                       const float* __restrict__ wwp,
                       const float* __restrict__ wwf,
                       const float* __restrict__ wdp,
                       float* __restrict__ ws)
{
    int f = threadIdx.x;
    float z = wwp[0] * p1[f] + wwp[1] * p2[f] + wwp[2] * p3[f];
    float weight = (z > 0.f) ? (1.f + z) : __expf(z);
    ws[WS_COEF + f] = wwf[0] * weight + wwf[1] * wdp[f];
}

__global__ __launch_bounds__(1024) void k_accum(
    const float* __restrict__ seq,
    const float* __restrict__ seq1,
    const int* __restrict__ labels,
    const float* __restrict__ a4p,
    float* __restrict__ ws)
{
    __shared__ int lsum[NC * FT];
    __shared__ int lcnt[NC];
    const int tid = threadIdx.x;
    for (int i = tid; i < NC * FT; i += 1024) lsum[i] = 0;
    if (tid < NC) lcnt[tid] = 0;
    __syncthreads();

    const int rr = tid >> 5;
    const int m  = tid & 31;
    const int f0 = m * 8;
    const int mh = m >> 2;
    int off[8];
#pragma unroll
    for (int i = 0; i < 8; ++i) off[i] = (i + mh) & 7;

    float cof[8];
    {
        const float4 c0 = *(const float4*)(ws + WS_COEF + f0);
        const float4 c1 = *(const float4*)(ws + WS_COEF + f0 + 4);
        cof[0]=c0.x; cof[1]=c0.y; cof[2]=c0.z; cof[3]=c0.w;
        cof[4]=c1.x; cof[5]=c1.y; cof[6]=c1.z; cof[7]=c1.w;
    }
    const float a4v = a4p[0];

    for (int row = blockIdx.x * 32 + rr; row < NROWS; row += gridDim.x * 32) {
        const int lab = labels[row];
        const float4 sa  = *(const float4*)(seq  + row * FT + f0);
        const float4 sb  = *(const float4*)(seq  + row * FT + f0 + 4);
        const float4 ta  = *(const float4*)(seq1 + row * FT + f0);
        const float4 tb  = *(const float4*)(seq1 + row * FT + f0 + 4);
        const float s[8]  = {sa.x,sa.y,sa.z,sa.w, sb.x,sb.y,sb.z,sb.w};
        const float t[8]  = {ta.x,ta.y,ta.z,ta.w, tb.x,tb.y,tb.z,tb.w};
        int* base = lsum + lab * FT + f0;
#pragma unroll
        for (int i = 0; i < 8; ++i) {
            float u = cof[i] * s[i];
            float r = (u > 0.f) ? u : (__expf(u) - 1.f);
            atomicAdd(base + off[i], __float2int_rn((r + a4v * t[i]) * FPSCALE));
        }
        if (m == 0) atomicAdd(&lcnt[lab], 1);
    }
    __syncthreads();

    int* gsum = (int*)(ws + WS_SUMS);
    for (int idx = tid; idx < NC * FT; idx += 1024) {
        int p  = idx & 255;
        int mm = p >> 3;
        int r  = p & 7;
        int f  = (p & ~7) | ((r - (mm >> 2)) & 7);
        atomicAdd(gsum + (idx & ~255) + f, lsum[idx]);
    }
    if (tid < NC) atomicAdd((int*)(ws + WS_CNTS) + tid, lcnt[tid]);
}

__global__ void k_final(float* __restrict__ ws)
{
    __shared__ float nacc[NC];
    const int f = threadIdx.x;
    if (f < NC) nacc[f] = 0.f;
    __syncthreads();
    const int* gsum = (const int*)(ws + WS_SUMS);
    const int* gcnt = (const int*)(ws + WS_CNTS);
    unsigned short* aveb = (unsigned short*)(ws + WS_AVEB);
#pragma unroll
    for (int c = 0; c < NC; ++c) {
        float cnt = (float)gcnt[c];
        float a = ((float)gsum[c * FT + f] * FPINV) / fmaxf(cnt, 1.f);
        unsigned short ab = f2bf(a);
        aveb[c * FT + f] = ab;
        float af = bfbits2f(ab);
        atomicAdd(&nacc[c], af * af);
    }
    __syncthreads();
    if (f < NC) ws[WS_NRM + f] = sqrtf(nacc[f]);
}

__global__ __launch_bounds__(256) void k_out(
    const float* __restrict__ seq,
    const float* __restrict__ seq1,
    const float* __restrict__ a4p,
    const float* __restrict__ ws,
    float* __restrict__ out)
{
    __shared__ __align__(16) float scoef[FT];
    const int tid = threadIdx.x;
    for (int i = tid; i < FT; i += 256) scoef[i] = ws[WS_COEF + i];
    __syncthreads();

    const int lane = tid & 63;
    const int wv   = tid >> 6;
    const int c = lane & 15;
    const int g = lane >> 4;

    const unsigned short* aveb = (const unsigned short*)(ws + WS_AVEB);
    bf16x8 bfrag[8];
#pragma unroll
    for (int kc = 0; kc < 8; ++kc)
        bfrag[kc] = *(const bf16x8*)(aveb + c * FT + kc * 32 + g * 8);
    const float na  = ws[WS_NRM + c];
    const float a4v = a4p[0];

    const int ntiles = NROWS / 16;
    for (int tile = blockIdx.x * 4 + wv; tile < ntiles; tile += gridDim.x * 4) {
        const int rowbase = tile * 16;
        const int arow = rowbase + c;
        f32x4 accC = {0.f, 0.f, 0.f, 0.f};
        f32x4 accS = {0.f, 0.f, 0.f, 0.f};
#pragma unroll
        for (int kc = 0; kc < 8; ++kc) {
            const int k0 = kc * 32 + g * 8;
            const float4 sa = *(const float4*)(seq  + arow * FT + k0);
            const float4 sb = *(const float4*)(seq  + arow * FT + k0 + 4);
            const float4 ta = *(const float4*)(seq1 + arow * FT + k0);
            const float4 tb = *(const float4*)(seq1 + arow * FT + k0 + 4);
            const float4 c0 = *(const float4*)(scoef + k0);
            const float4 c1 = *(const float4*)(scoef + k0 + 4);
            const float s[8]  = {sa.x,sa.y,sa.z,sa.w, sb.x,sb.y,sb.z,sb.w};
            const float t[8]  = {ta.x,ta.y,ta.z,ta.w, tb.x,tb.y,tb.z,tb.w};
            const float cf[8] = {c0.x,c0.y,c0.z,c0.w, c1.x,c1.y,c1.z,c1.w};
            bf16x8 afrag;
#pragma unroll
            for (int i = 0; i < 8; ++i) {
                float u = cf[i] * s[i];
                float r = (u > 0.f) ? u : (__expf(u) - 1.f);
                afrag[i] = (short)f2bf(r + a4v * t[i]);
            }
            accC = __builtin_amdgcn_mfma_f32_16x16x32_bf16(afrag, bfrag[kc], accC, 0, 0, 0);
            accS = __builtin_amdgcn_mfma_f32_16x16x32_bf16(afrag, afrag,     accS, 0, 0, 0);
        }
#pragma unroll
        for (int q = 0; q < 4; ++q) {
            const float sd = __shfl(accS[q], g * 20 + q, 64);
            const float nr = sqrtf(fmaxf(sd, 0.f));
            const float denom = fmaxf(nr * na, 1e-8f);
            float cosv = accC[q] / denom;
            float mx = cosv;
#pragma unroll
            for (int o = 1; o < 16; o <<= 1) mx = fmaxf(mx, __shfl_xor(mx, o, 16));
            const float e = __expf(cosv - mx);
            float s = e;
#pragma unroll
            for (int o = 1; o < 16; o <<= 1) s += __shfl_xor(s, o, 16);
            out[(rowbase + g * 4 + q) * NC + c] = e / s;
        }
    }
}

extern "C" void kernel_launch(void* const* d_in, const int* in_sizes, int n_in,
                              void* d_out, int out_size, void* d_ws, size_t ws_size,
                              hipStream_t stream)
{
    const float* seq  = (const float*)d_in[0];
    const float* seq1 = (const float*)d_in[1];
    const int*   lab  = (const int*)d_in[2];
    const float* p1   = (const float*)d_in[3];
    const float* p2   = (const float*)d_in[4];
    const float* p3   = (const float*)d_in[5];
    const float* wwp  = (const float*)d_in[6];
    const float* wwf  = (const float*)d_in[7];
    const float* wdp  = (const float*)d_in[8];
    const float* a4   = (const float*)d_in[9];
    float* ws  = (float*)d_ws;
    float* out = (float*)d_out;

    if (ws_size >= CACHED2_NEED_BYTES) {
        // full path: NT input loads + row-norm precompute (half MFMAs in out)
        k_accum_ct<1><<<NBLK,     256, 0, stream>>>(seq, seq1, lab, p1, p2, p3,
                                                    wwp, wwf, wdp, a4, ws);
        k_reduce1   <<<NC * NSL,  256, 0, stream>>>(ws);
        k_reduce2   <<<NC,        256, 0, stream>>>(ws);
        k_out_ct<1> <<<1568,      256, 0, stream>>>(ws, out);
    } else if (ws_size >= CACHED_NEED_BYTES) {
        // middle: same chain without the nrm2 region
        k_accum_ct<0><<<NBLK,     256, 0, stream>>>(seq, seq1, lab, p1, p2, p3,
                                                    wwp, wwf, wdp, a4, ws);
        k_reduce1   <<<NC * NSL,  256, 0, stream>>>(ws);
        k_reduce2   <<<NC,        256, 0, stream>>>(ws);
        k_out_ct<0> <<<1568,      256, 0, stream>>>(ws, out);
    } else {
        // fallback: R3 structure
        hipMemsetAsync((char*)d_ws + WS_SUMS * sizeof(int), 0,
                       (NC * FT + NC) * sizeof(int), stream);
        k_prep <<<1,    256, 0, stream>>>(p1, p2, p3, wwp, wwf, wdp, ws);
        k_accum<<<512, 1024, 0, stream>>>(seq, seq1, lab, a4, ws);
        k_final<<<1,    256, 0, stream>>>(ws);
        k_out  <<<1568, 256, 0, stream>>>(seq, seq1, a4, ws, out);
    }
}